// Round 6
// baseline (1249.827 us; speedup 1.0000x reference)
//
#include <hip/hip_runtime.h>
#include <math.h>

#define NNODE 100
#define NEGV  -1000000000.0f

// ---------------- static device workspace (ws_size unknown -> avoid d_ws) ---
__device__ float g_Wall [128 * 512];            // [k][c]: Wk^T | Wv^T | G | M^T
__device__ float g_Wall2[128 * 128];            // [k][c]: (Wq@fc1_w)^T
__device__ float g_qcap [128];                  // Wq @ fc_w[:,H]
__device__ float g_C    [(size_t)102400 * 512]; // per (b,n): K|V|K2W|Q1
__device__ float g_qpool[(size_t)1024 * 128];   // per b
__device__ float g_S1   [(size_t)1024 * 100 * 800]; // [b][m][h*100+n]
__device__ float g_Scap [(size_t)1024 * 800];       // [b][h*100+n]

__device__ __forceinline__ float fast_rcp(float x) { return __builtin_amdgcn_rcpf(x); }
__device__ __forceinline__ float tanh10(float z) {
    // 10*tanh(z) = 10 - 20/(exp(2z)+1); exp->inf => 10, exp->0 => -10 (safe)
    const float e2 = __expf(2.0f * z);
    return fmaf(-20.0f, __builtin_amdgcn_rcpf(e2 + 1.0f), 10.0f);
}

// ---------------- kernel 1: fold weights -----------------------------------
__global__ __launch_bounds__(128) void prep_kernel(
    const float* __restrict__ Wk,  const float* __restrict__ Wv,
    const float* __restrict__ Wk2, const float* __restrict__ Wo,
    const float* __restrict__ Wq,  const float* __restrict__ fc_w,
    const float* __restrict__ fc1_w)
{
    const int c = blockIdx.x;
    const int k = threadIdx.x;
    if (c < 128) {
        g_Wall[k * 512 + c] = Wk[c * 128 + k];
    } else if (c < 256) {
        g_Wall[k * 512 + c] = Wv[(c - 128) * 128 + k];
    } else if (c < 384) {                           // G = Wk2^T @ Wo
        const int cc = c - 256;
        float acc = 0.f;
        for (int h = 0; h < 128; h++)
            acc = fmaf(Wk2[h * 128 + k], Wo[h * 128 + cc], acc);
        g_Wall[k * 512 + c] = acc;
    } else if (c < 512) {                           // M^T, M = Wq@fc_w[:,:128]
        const int cc = c - 384;
        float acc = 0.f;
        for (int j = 0; j < 128; j++)
            acc = fmaf(Wq[cc * 128 + j], fc_w[j * 129 + k], acc);
        g_Wall[k * 512 + c] = acc;
    } else if (c == 512) {                          // qcap = Wq @ fc_w[:,128]
        float acc = 0.f;
        for (int j = 0; j < 128; j++)
            acc = fmaf(Wq[k * 128 + j], fc_w[j * 129 + 128], acc);
        g_qcap[k] = acc;
    } else {                                        // (Wq@fc1_w)^T
        const int cc = c - 513;
        float acc = 0.f;
        for (int j = 0; j < 128; j++)
            acc = fmaf(Wq[cc * 128 + j], fc1_w[j * 128 + k], acc);
        g_Wall2[k * 128 + cc] = acc;
    }
}

// ---------------- kernel 2: fp32 tiled GEMM, k-chunked (33 KB LDS) ----------
__global__ __launch_bounds__(256) void gemm_kernel(const float* __restrict__ A,
                                                   int mode)
{
    const float* __restrict__ W = mode ? g_Wall2 : g_Wall;
    float* __restrict__ C       = mode ? g_qpool : g_C;
    const int ncols             = mode ? 128 : 512;
    const int m0 = blockIdx.x * 128, n0 = blockIdx.y * 128;

    __shared__ __align__(16) float At[32 * 132];   // [k_local][m]
    __shared__ __align__(16) float Ws[32 * 128];   // [k_local][n]
    const int tid = threadIdx.x;
    const int tm = tid >> 5, tn = tid & 31;
    const int mb = tm * 16, nb = tn * 4;
    float4 acc[16];
#pragma unroll
    for (int i = 0; i < 16; i++) acc[i] = make_float4(0.f, 0.f, 0.f, 0.f);

    for (int kc = 0; kc < 4; kc++) {
        for (int f = tid; f < 1024; f += 256) {
            const int r = f >> 3, q8 = f & 7;
            float4 a = *(const float4*)&A[(size_t)(m0 + r) * 128 + kc * 32 + q8 * 4];
            At[(q8 * 4 + 0) * 132 + r] = a.x;
            At[(q8 * 4 + 1) * 132 + r] = a.y;
            At[(q8 * 4 + 2) * 132 + r] = a.z;
            At[(q8 * 4 + 3) * 132 + r] = a.w;
            const int kl = f >> 5, q = f & 31;
            *(float4*)&Ws[kl * 128 + q * 4] =
                *(const float4*)&W[(size_t)(kc * 32 + kl) * ncols + n0 + q * 4];
        }
        __syncthreads();
        for (int k = 0; k < 32; k++) {
            const float4 w = *(float4*)&Ws[k * 128 + nb];
#pragma unroll
            for (int i = 0; i < 16; i += 4) {
                const float4 a = *(float4*)&At[k * 132 + mb + i];
                acc[i + 0].x = fmaf(a.x, w.x, acc[i + 0].x);
                acc[i + 0].y = fmaf(a.x, w.y, acc[i + 0].y);
                acc[i + 0].z = fmaf(a.x, w.z, acc[i + 0].z);
                acc[i + 0].w = fmaf(a.x, w.w, acc[i + 0].w);
                acc[i + 1].x = fmaf(a.y, w.x, acc[i + 1].x);
                acc[i + 1].y = fmaf(a.y, w.y, acc[i + 1].y);
                acc[i + 1].z = fmaf(a.y, w.z, acc[i + 1].z);
                acc[i + 1].w = fmaf(a.y, w.w, acc[i + 1].w);
                acc[i + 2].x = fmaf(a.z, w.x, acc[i + 2].x);
                acc[i + 2].y = fmaf(a.z, w.y, acc[i + 2].y);
                acc[i + 2].z = fmaf(a.z, w.z, acc[i + 2].z);
                acc[i + 2].w = fmaf(a.z, w.w, acc[i + 2].w);
                acc[i + 3].x = fmaf(a.w, w.x, acc[i + 3].x);
                acc[i + 3].y = fmaf(a.w, w.y, acc[i + 3].y);
                acc[i + 3].z = fmaf(a.w, w.z, acc[i + 3].z);
                acc[i + 3].w = fmaf(a.w, w.w, acc[i + 3].w);
            }
        }
        __syncthreads();
    }
#pragma unroll
    for (int i = 0; i < 16; i++)
        *(float4*)&C[(size_t)(m0 + mb + i) * ncols + n0 + nb] = acc[i];
}

// ---------------- kernel 2.5: per-batch score fold --------------------------
__global__ __launch_bounds__(256) void s1_kernel()
{
    const int b = blockIdx.x;
    const int tid = threadIdx.x;
    const int h = tid >> 5, l32 = tid & 31;
    const float* __restrict__ Crow = &g_C[(size_t)b * 100 * 512];

    __shared__ __align__(16) float Q1sh[NNODE * 128];
    for (int f = tid; f < 3200; f += 256) {
        const int n = f >> 5, c4 = f & 31;
        *(float4*)&Q1sh[n * 128 + c4 * 4] =
            *(const float4*)&Crow[(size_t)n * 512 + 384 + c4 * 4];
    }
    __syncthreads();

    float4 kr[4][4];
    int nn[4];
#pragma unroll
    for (int j = 0; j < 4; j++) {
        nn[j] = l32 + 32 * j;
#pragma unroll
        for (int i = 0; i < 4; i++) {
            kr[j][i] = (nn[j] < 100)
                ? *(const float4*)&Crow[(size_t)nn[j] * 512 + h * 16 + i * 4]
                : make_float4(0.f, 0.f, 0.f, 0.f);
        }
    }
    float4 qc[4], qp[4];
#pragma unroll
    for (int i = 0; i < 4; i++) {
        qc[i] = *(const float4*)&g_qcap[h * 16 + i * 4];
        qp[i] = *(const float4*)&g_qpool[(size_t)b * 128 + h * 16 + i * 4];
    }
    float sp[4];
#pragma unroll
    for (int j = 0; j < 4; j++) {
        float dc = 0.f, dp = 0.f;
#pragma unroll
        for (int i = 0; i < 4; i++) {
            dc = fmaf(kr[j][i].x, qc[i].x, dc); dc = fmaf(kr[j][i].y, qc[i].y, dc);
            dc = fmaf(kr[j][i].z, qc[i].z, dc); dc = fmaf(kr[j][i].w, qc[i].w, dc);
            dp = fmaf(kr[j][i].x, qp[i].x, dp); dp = fmaf(kr[j][i].y, qp[i].y, dp);
            dp = fmaf(kr[j][i].z, qp[i].z, dp); dp = fmaf(kr[j][i].w, qp[i].w, dp);
        }
        sp[j] = dp;
        if (nn[j] < 100)
            g_Scap[(size_t)b * 800 + h * 100 + nn[j]] = dc * 0.25f;
    }

    float* __restrict__ S1b = &g_S1[(size_t)b * 80000];
    for (int m = 0; m < 100; m++) {
        float4 q[4];
#pragma unroll
        for (int i = 0; i < 4; i++)
            q[i] = *(float4*)&Q1sh[m * 128 + h * 16 + i * 4];
#pragma unroll
        for (int j = 0; j < 4; j++) {
            if (nn[j] < 100) {
                float d = 0.f;
#pragma unroll
                for (int i = 0; i < 4; i++) {
                    d = fmaf(kr[j][i].x, q[i].x, d); d = fmaf(kr[j][i].y, q[i].y, d);
                    d = fmaf(kr[j][i].z, q[i].z, d); d = fmaf(kr[j][i].w, q[i].w, d);
                }
                S1b[(size_t)m * 800 + h * 100 + nn[j]] = (d + sp[j]) * 0.25f;
            }
        }
    }
}

// ---------------- kernel 3: decode, 512 threads = 8 waves = 1 wave/head -----
// wave w owns head w entirely: scores+softmax intra-wave (nodes l, l+64),
// glimpse over V[:, head-w cols] (lane = (f2=l>>4 chunk, g2=l&15 node-residue)),
// u-partials for head-w's 16 cols; only u crosses waves (1 barrier/step).
__global__ __launch_bounds__(512, 4) void decode_kernel(
    const float* __restrict__ capacity, const float* __restrict__ demand,
    const int* __restrict__ nsteps_p, const int* __restrict__ T_p,
    float* __restrict__ out)
{
    __shared__ float u_buf[2 * 800];    // [parity][w<8][n<100]
    __shared__ int   act_sh[512];

    const int tid = threadIdx.x;
    const int b   = blockIdx.x;
    const int nsteps = nsteps_p[0];
    const float invT = 1.0f / (float)T_p[0];
    const float base_cap = capacity[0];
    const float inv_sqrt_h = 0.08838834764831845f;  // 1/sqrt(128)

    const float4* __restrict__ C4  = (const float4*)&g_C[(size_t)b * 100 * 512];
    const float*  __restrict__ S1b = &g_S1[(size_t)b * 80000];

    const int w = tid >> 6, l = tid & 63;
    const int f2 = l >> 4, g2 = l & 15;     // C/U mapping: chunk f2, residue g2
    const int NM = (g2 < 4) ? 7 : 6;        // nodes g2+16m < 100

    // ---- persistent registers (V, K2W fragments for head w)
    float4 Vreg[7], K2r[7];
#pragma unroll
    for (int m = 0; m < 7; m++) {
        const int n = g2 + 16 * m;
        const bool v = n < 100;
        Vreg[m] = v ? C4[(size_t)n * 128 + 32 + 4 * w + f2]
                    : make_float4(0.f, 0.f, 0.f, 0.f);
        K2r[m]  = v ? C4[(size_t)n * 128 + 64 + 4 * w + f2]
                    : make_float4(0.f, 0.f, 0.f, 0.f);
    }
    // per-lane nodes l and l+64 (shared by B and E phases)
    const bool has1 = (l + 64 < 100);
    const float de0 = demand[b * 100 + l];
    const float de1 = has1 ? demand[b * 100 + l + 64] : 1.0e30f;
    float scap0 = g_Scap[(size_t)b * 800 + w * 100 + l];
    float scap1 = has1 ? g_Scap[(size_t)b * 800 + w * 100 + l + 64] : 0.f;
    float s1r0 = S1b[w * 100 + l];                      // prev = 0 row
    float s1r1 = has1 ? S1b[w * 100 + l + 64] : 0.f;
    bool me0 = false, me1 = false;
    float cap_r = capacity[b];
    float depot_r;
    {
        const bool am0 = (l == 0) ? true : (de0 > cap_r);
        const bool am1 = has1 ? (de1 > cap_r) : true;
        depot_r = __all(am0 && am1) ? 0.f : 1.f;
    }
    float logp_r = 0.f;
    int visited_r = 0;
    int ub = 0;

    for (int s = 0; s < nsteps; s++) {
        const float cap = cap_r;

        // ---- B: masked scores + exp (no max-sub: |s|<~30 stat-bounded,
        //      masked -> exp(-1e9)=0 exactly; reference max-sub is a no-op)
        float e0, e1;
        {
            const bool m0 = (l == 0) ? (depot_r != 0.f) : (me0 || de0 > cap);
            const float r0 = fmaf(cap, scap0, s1r0);
            e0 = __expf(m0 ? NEGV : r0);
            const bool m1 = me1 || de1 > cap;
            const float r1 = fmaf(cap, scap1, s1r1);
            e1 = (has1 && !m1) ? __expf(r1) : 0.f;
        }

        // ---- C: glimpse chunk f2 of head w (attn intra-wave via shfl);
        //      tot butterfly overlaps the shfl-FMA chain
        float4 gp4 = make_float4(0.f, 0.f, 0.f, 0.f);
        float tot = e0 + e1;
#pragma unroll
        for (int m = 0; m < 7; m++) {
            const int src = (m < 4) ? (g2 + 16 * m) : (g2 + 16 * (m - 4));
            const float av = __shfl((m < 4) ? e0 : e1, src, 64);
            gp4.x = fmaf(av, Vreg[m].x, gp4.x);
            gp4.y = fmaf(av, Vreg[m].y, gp4.y);
            gp4.z = fmaf(av, Vreg[m].z, gp4.z);
            gp4.w = fmaf(av, Vreg[m].w, gp4.w);
        }
#pragma unroll
        for (int off = 1; off <= 32; off <<= 1) tot += __shfl_xor(tot, off, 64);
#pragma unroll
        for (int off = 1; off <= 8; off <<= 1) {
            gp4.x += __shfl_xor(gp4.x, off, 64);
            gp4.y += __shfl_xor(gp4.y, off, 64);
            gp4.z += __shfl_xor(gp4.z, off, 64);
            gp4.w += __shfl_xor(gp4.w, off, 64);
        }
        {
            const float rt = fast_rcp(tot);
            gp4.x *= rt; gp4.y *= rt; gp4.z *= rt; gp4.w *= rt;
        }

        // ---- U: u-partials (head-w's 16 cols) for all nodes -> u_buf[w]
        {
            float pm[7];
#pragma unroll
            for (int m = 0; m < 7; m++) {
                float p = gp4.x * K2r[m].x;
                p = fmaf(gp4.y, K2r[m].y, p);
                p = fmaf(gp4.z, K2r[m].z, p);
                p = fmaf(gp4.w, K2r[m].w, p);
                pm[m] = p;
            }
#pragma unroll
            for (int m = 0; m < 7; m++) pm[m] += __shfl_xor(pm[m], 16, 64);
#pragma unroll
            for (int m = 0; m < 7; m++) pm[m] += __shfl_xor(pm[m], 32, 64);
            if (f2 == 0) {
#pragma unroll
                for (int m = 0; m < 7; m++) {
                    if (m < NM) u_buf[ub + w * 100 + g2 + 16 * m] = pm[m];
                }
            }
        }
        __syncthreads();

        // ---- E: redundant per-wave: sum 8 head-partials, tanh, argmax, lse
        float v0, v1 = -3.0e38f;
        {
            float s8 = 0.f;
#pragma unroll
            for (int r = 0; r < 8; r++) s8 += u_buf[ub + r * 100 + l];
            const float u0 = tanh10(s8 * inv_sqrt_h);
            const bool m0 = (l == 0) ? (depot_r != 0.f) : (me0 || de0 > cap);
            v0 = (m0 ? NEGV : u0) * invT;
            if (has1) {
                float t8 = 0.f;
#pragma unroll
                for (int r = 0; r < 8; r++) t8 += u_buf[ub + r * 100 + l + 64];
                const float u1 = tanh10(t8 * inv_sqrt_h);
                const bool m1 = (me1 || de1 > cap);
                v1 = (m1 ? NEGV : u1) * invT;
            }
        }
        float bv; int bi;
        if (v1 > v0) { bv = v1; bi = l + 64; } else { bv = v0; bi = l; }
#pragma unroll
        for (int off = 1; off < 64; off <<= 1) {
            const float ov = __shfl_xor(bv, off, 64);
            const int   oi = __shfl_xor(bi, off, 64);
            if (ov > bv || (ov == bv && oi < bi)) { bv = ov; bi = oi; }
        }
        const int idx = bi;

        // prefetch next S1 row ASAP (lse butterfly + state hide the load)
        s1r0 = S1b[(size_t)idx * 800 + w * 100 + l];
        if (has1) s1r1 = S1b[(size_t)idx * 800 + w * 100 + l + 64];

        float tt = __expf(v0 - bv) + (has1 ? __expf(v1 - bv) : 0.f);
#pragma unroll
        for (int off = 1; off < 64; off <<= 1) tt += __shfl_xor(tt, off, 64);

        const float d_sel = (idx >= 64) ? de1 : de0;
        const float dmd_idx = __shfl(d_sel, idx & 63, 64);
        const float capn = (idx == 0) ? base_cap : (cap - dmd_idx);

        if (visited_r < 99) logp_r += -__logf(tt);
        visited_r += (idx > 0) ? 1 : 0;
        me0 = me0 || (l == idx && idx > 0);
        me1 = me1 || (l + 64 == idx);

        const bool am0 = (l == 0) ? true : (me0 || de0 > capn);
        const bool am1 = has1 ? (me1 || de1 > capn) : true;
        const bool allc = __all(am0 && am1);
        depot_r = allc ? 0.f : ((idx == 0) ? 1.f : 0.f);
        cap_r = capn;
        if (tid == 0) act_sh[s] = idx;
        ub ^= 800;
    }

    __syncthreads();
    for (int t = tid; t < nsteps; t += 512)
        out[(size_t)b * nsteps + t] = (float)act_sh[t];
    if (tid == 0)
        out[(size_t)gridDim.x * nsteps + b] = logp_r;
}

// ---------------- launcher ---------------------------------------------------
extern "C" void kernel_launch(void* const* d_in, const int* in_sizes, int n_in,
                              void* d_out, int out_size, void* d_ws, size_t ws_size,
                              hipStream_t stream) {
    const float* enc    = (const float*)d_in[0];
    const float* pool   = (const float*)d_in[1];
    const float* cap    = (const float*)d_in[2];
    const float* demand = (const float*)d_in[3];
    const float* fc_w   = (const float*)d_in[4];
    const float* fc1_w  = (const float*)d_in[5];
    const float* Wq     = (const float*)d_in[6];
    const float* Wk     = (const float*)d_in[7];
    const float* Wv     = (const float*)d_in[8];
    const float* Wo     = (const float*)d_in[9];
    const float* Wk2    = (const float*)d_in[10];
    const int*   nst    = (const int*)d_in[11];
    const int*   Tp     = (const int*)d_in[12];
    float* out = (float*)d_out;

    prep_kernel<<<641, 128, 0, stream>>>(Wk, Wv, Wk2, Wo, Wq, fc_w, fc1_w);
    gemm_kernel<<<dim3(800, 4), 256, 0, stream>>>(enc, 0);
    gemm_kernel<<<dim3(8, 1),   256, 0, stream>>>(pool, 1);
    s1_kernel<<<1024, 256, 0, stream>>>();
    decode_kernel<<<1024, 512, 0, stream>>>(cap, demand, nst, Tp, out);
}

// Round 7
// 1023.368 us; speedup vs baseline: 1.2213x; 1.2213x over previous
//
#include <hip/hip_runtime.h>
#include <math.h>

#define NNODE 100
#define NEGV  -1000000000.0f

// ---------------- static device workspace (ws_size unknown -> avoid d_ws) ---
__device__ float g_Wall [128 * 512];            // [k][c]: Wk^T | Wv^T | G | M^T
__device__ float g_Wall2[128 * 128];            // [k][c]: (Wq@fc1_w)^T
__device__ float g_qcap [128];                  // Wq @ fc_w[:,H]
__device__ float g_C    [(size_t)102400 * 512]; // per (b,n): K|V|K2W|Q1
__device__ float g_qpool[(size_t)1024 * 128];   // per b
__device__ float g_S1   [(size_t)1024 * 100 * 800]; // [b][m][h*100+n]
__device__ float g_Scap [(size_t)1024 * 800];       // [b][h*100+n]

__device__ __forceinline__ float fast_rcp(float x) { return __builtin_amdgcn_rcpf(x); }
__device__ __forceinline__ float tanh10(float z) {
    // 10*tanh(z) = 10 - 20/(exp(2z)+1); exp->inf => 10, exp->0 => -10 (safe)
    const float e2 = __expf(2.0f * z);
    return fmaf(-20.0f, __builtin_amdgcn_rcpf(e2 + 1.0f), 10.0f);
}
// monotone order-preserving float->uint key (totally ordered, no NaNs here)
__device__ __forceinline__ unsigned fkey(float v) {
    const unsigned u = __float_as_uint(v);
    return (u & 0x80000000u) ? ~u : (u | 0x80000000u);
}
__device__ __forceinline__ float funkey(unsigned k) {
    return __uint_as_float((k & 0x80000000u) ? (k ^ 0x80000000u) : ~k);
}

// ---------------- kernel 1: fold weights -----------------------------------
__global__ __launch_bounds__(128) void prep_kernel(
    const float* __restrict__ Wk,  const float* __restrict__ Wv,
    const float* __restrict__ Wk2, const float* __restrict__ Wo,
    const float* __restrict__ Wq,  const float* __restrict__ fc_w,
    const float* __restrict__ fc1_w)
{
    const int c = blockIdx.x;
    const int k = threadIdx.x;
    if (c < 128) {
        g_Wall[k * 512 + c] = Wk[c * 128 + k];
    } else if (c < 256) {
        g_Wall[k * 512 + c] = Wv[(c - 128) * 128 + k];
    } else if (c < 384) {                           // G = Wk2^T @ Wo
        const int cc = c - 256;
        float acc = 0.f;
        for (int h = 0; h < 128; h++)
            acc = fmaf(Wk2[h * 128 + k], Wo[h * 128 + cc], acc);
        g_Wall[k * 512 + c] = acc;
    } else if (c < 512) {                           // M^T, M = Wq@fc_w[:,:128]
        const int cc = c - 384;
        float acc = 0.f;
        for (int j = 0; j < 128; j++)
            acc = fmaf(Wq[cc * 128 + j], fc_w[j * 129 + k], acc);
        g_Wall[k * 512 + c] = acc;
    } else if (c == 512) {                          // qcap = Wq @ fc_w[:,128]
        float acc = 0.f;
        for (int j = 0; j < 128; j++)
            acc = fmaf(Wq[k * 128 + j], fc_w[j * 129 + 128], acc);
        g_qcap[k] = acc;
    } else {                                        // (Wq@fc1_w)^T
        const int cc = c - 513;
        float acc = 0.f;
        for (int j = 0; j < 128; j++)
            acc = fmaf(Wq[cc * 128 + j], fc1_w[j * 128 + k], acc);
        g_Wall2[k * 128 + cc] = acc;
    }
}

// ---------------- kernel 2: fp32 tiled GEMM, k-chunked (33 KB LDS) ----------
__global__ __launch_bounds__(256) void gemm_kernel(const float* __restrict__ A,
                                                   int mode)
{
    const float* __restrict__ W = mode ? g_Wall2 : g_Wall;
    float* __restrict__ C       = mode ? g_qpool : g_C;
    const int ncols             = mode ? 128 : 512;
    const int m0 = blockIdx.x * 128, n0 = blockIdx.y * 128;

    __shared__ __align__(16) float At[32 * 132];   // [k_local][m]
    __shared__ __align__(16) float Ws[32 * 128];   // [k_local][n]
    const int tid = threadIdx.x;
    const int tm = tid >> 5, tn = tid & 31;
    const int mb = tm * 16, nb = tn * 4;
    float4 acc[16];
#pragma unroll
    for (int i = 0; i < 16; i++) acc[i] = make_float4(0.f, 0.f, 0.f, 0.f);

    for (int kc = 0; kc < 4; kc++) {
        for (int f = tid; f < 1024; f += 256) {
            const int r = f >> 3, q8 = f & 7;
            float4 a = *(const float4*)&A[(size_t)(m0 + r) * 128 + kc * 32 + q8 * 4];
            At[(q8 * 4 + 0) * 132 + r] = a.x;
            At[(q8 * 4 + 1) * 132 + r] = a.y;
            At[(q8 * 4 + 2) * 132 + r] = a.z;
            At[(q8 * 4 + 3) * 132 + r] = a.w;
            const int kl = f >> 5, q = f & 31;
            *(float4*)&Ws[kl * 128 + q * 4] =
                *(const float4*)&W[(size_t)(kc * 32 + kl) * ncols + n0 + q * 4];
        }
        __syncthreads();
        for (int k = 0; k < 32; k++) {
            const float4 w = *(float4*)&Ws[k * 128 + nb];
#pragma unroll
            for (int i = 0; i < 16; i += 4) {
                const float4 a = *(float4*)&At[k * 132 + mb + i];
                acc[i + 0].x = fmaf(a.x, w.x, acc[i + 0].x);
                acc[i + 0].y = fmaf(a.x, w.y, acc[i + 0].y);
                acc[i + 0].z = fmaf(a.x, w.z, acc[i + 0].z);
                acc[i + 0].w = fmaf(a.x, w.w, acc[i + 0].w);
                acc[i + 1].x = fmaf(a.y, w.x, acc[i + 1].x);
                acc[i + 1].y = fmaf(a.y, w.y, acc[i + 1].y);
                acc[i + 1].z = fmaf(a.y, w.z, acc[i + 1].z);
                acc[i + 1].w = fmaf(a.y, w.w, acc[i + 1].w);
                acc[i + 2].x = fmaf(a.z, w.x, acc[i + 2].x);
                acc[i + 2].y = fmaf(a.z, w.y, acc[i + 2].y);
                acc[i + 2].z = fmaf(a.z, w.z, acc[i + 2].z);
                acc[i + 2].w = fmaf(a.z, w.w, acc[i + 2].w);
                acc[i + 3].x = fmaf(a.w, w.x, acc[i + 3].x);
                acc[i + 3].y = fmaf(a.w, w.y, acc[i + 3].y);
                acc[i + 3].z = fmaf(a.w, w.z, acc[i + 3].z);
                acc[i + 3].w = fmaf(a.w, w.w, acc[i + 3].w);
            }
        }
        __syncthreads();
    }
#pragma unroll
    for (int i = 0; i < 16; i++)
        *(float4*)&C[(size_t)(m0 + mb + i) * ncols + n0 + nb] = acc[i];
}

// ---------------- kernel 2.5: per-batch score fold --------------------------
__global__ __launch_bounds__(256) void s1_kernel()
{
    const int b = blockIdx.x;
    const int tid = threadIdx.x;
    const int h = tid >> 5, l32 = tid & 31;
    const float* __restrict__ Crow = &g_C[(size_t)b * 100 * 512];

    __shared__ __align__(16) float Q1sh[NNODE * 128];
    for (int f = tid; f < 3200; f += 256) {
        const int n = f >> 5, c4 = f & 31;
        *(float4*)&Q1sh[n * 128 + c4 * 4] =
            *(const float4*)&Crow[(size_t)n * 512 + 384 + c4 * 4];
    }
    __syncthreads();

    float4 kr[4][4];
    int nn[4];
#pragma unroll
    for (int j = 0; j < 4; j++) {
        nn[j] = l32 + 32 * j;
#pragma unroll
        for (int i = 0; i < 4; i++) {
            kr[j][i] = (nn[j] < 100)
                ? *(const float4*)&Crow[(size_t)nn[j] * 512 + h * 16 + i * 4]
                : make_float4(0.f, 0.f, 0.f, 0.f);
        }
    }
    float4 qc[4], qp[4];
#pragma unroll
    for (int i = 0; i < 4; i++) {
        qc[i] = *(const float4*)&g_qcap[h * 16 + i * 4];
        qp[i] = *(const float4*)&g_qpool[(size_t)b * 128 + h * 16 + i * 4];
    }
    float sp[4];
#pragma unroll
    for (int j = 0; j < 4; j++) {
        float dc = 0.f, dp = 0.f;
#pragma unroll
        for (int i = 0; i < 4; i++) {
            dc = fmaf(kr[j][i].x, qc[i].x, dc); dc = fmaf(kr[j][i].y, qc[i].y, dc);
            dc = fmaf(kr[j][i].z, qc[i].z, dc); dc = fmaf(kr[j][i].w, qc[i].w, dc);
            dp = fmaf(kr[j][i].x, qp[i].x, dp); dp = fmaf(kr[j][i].y, qp[i].y, dp);
            dp = fmaf(kr[j][i].z, qp[i].z, dp); dp = fmaf(kr[j][i].w, qp[i].w, dp);
        }
        sp[j] = dp;
        if (nn[j] < 100)
            g_Scap[(size_t)b * 800 + h * 100 + nn[j]] = dc * 0.25f;
    }

    float* __restrict__ S1b = &g_S1[(size_t)b * 80000];
    for (int m = 0; m < 100; m++) {
        float4 q[4];
#pragma unroll
        for (int i = 0; i < 4; i++)
            q[i] = *(float4*)&Q1sh[m * 128 + h * 16 + i * 4];
#pragma unroll
        for (int j = 0; j < 4; j++) {
            if (nn[j] < 100) {
                float d = 0.f;
#pragma unroll
                for (int i = 0; i < 4; i++) {
                    d = fmaf(kr[j][i].x, q[i].x, d); d = fmaf(kr[j][i].y, q[i].y, d);
                    d = fmaf(kr[j][i].z, q[i].z, d); d = fmaf(kr[j][i].w, q[i].w, d);
                }
                S1b[(size_t)m * 800 + h * 100 + nn[j]] = (d + sp[j]) * 0.25f;
            }
        }
    }
}

// ---------------- kernel 3: sequential decode, 1 barrier/step ----------------
// R5 layout (256t, wave w owns heads {2w,2w+1} / gp cols 32w..32w+31) with
// shortened serial chain: no max-sub, tot butterfly overlapped with glimpse,
// argmax+lse fused into one packed-u64 butterfly.
__global__ __launch_bounds__(256) void decode_kernel(
    const float* __restrict__ capacity, const float* __restrict__ demand,
    const int* __restrict__ nsteps_p, const int* __restrict__ T_p,
    float* __restrict__ out)
{
    __shared__ float u_buf[2 * 800];    // [parity][r<8][n<100]
    __shared__ int   act_sh[512];

    const int tid = threadIdx.x;
    const int b   = blockIdx.x;
    const int nsteps = nsteps_p[0];
    const float invT = 1.0f / (float)T_p[0];
    const float base_cap = capacity[0];
    const float inv_sqrt_h = 0.08838834764831845f;  // 1/sqrt(128)

    const float4* __restrict__ C4  = (const float4*)&g_C[(size_t)b * 100 * 512];
    const float*  __restrict__ S1b = &g_S1[(size_t)b * 80000];

    const int w = tid >> 6, l = tid & 63;
    const int g = l >> 3, f = l & 7;
    const int F = 8 * w + f;                 // global float4 col 0..31
    const int h8 = tid >> 5, l32 = tid & 31; // B mapping: head h8, nodes l32+32j

    // ---- persistent registers
    float4 Vreg[13], K2r[13];
#pragma unroll
    for (int m = 0; m < 13; m++) {
        const int n = g + 8 * m;
        const bool v = n < 100;
        Vreg[m] = v ? C4[(size_t)n * 128 + 32 + F] : make_float4(0.f, 0.f, 0.f, 0.f);
        K2r[m]  = v ? C4[(size_t)n * 128 + 64 + F] : make_float4(0.f, 0.f, 0.f, 0.f);
    }
    float s1r[4], scapr[4], d4[4];
#pragma unroll
    for (int j = 0; j < 4; j++) {
        const int nj = l32 + 32 * j;
        const bool v = nj < 100;
        scapr[j] = v ? g_Scap[(size_t)b * 800 + h8 * 100 + nj] : 0.f;
        s1r[j]   = v ? S1b[h8 * 100 + nj] : 0.f;
        d4[j]    = v ? demand[b * 100 + nj] : 1.0e30f;
    }
    const float de0 = demand[b * 100 + l];
    const float de1 = (l + 64 < 100) ? demand[b * 100 + l + 64] : 1.0e30f;
    bool me0 = false, me1 = false;      // mask1 for nodes l, l+64
    unsigned mb4 = 0;                   // mask1 bits for B's 4 nodes
    float cap_r = capacity[b];
    float depot_r;
    {
        const bool am0 = (l == 0) ? true : (de0 > cap_r);
        const bool am1 = (l + 64 >= 100) ? true : (de1 > cap_r);
        depot_r = __all(am0 && am1) ? 0.f : 1.f;
    }
    float logp_r = 0.f;
    int visited_r = 0;
    int ub = 0;

    for (int s = 0; s < nsteps; s++) {
        const float cap = cap_r;

        // ---- B: masked scores + raw exp (no max-sub: scores stat-bounded,
        //      masked -> exp(-1e9)=0 exact; proven in R6 at absmax 0)
        float a[4];
        float tot;
        {
            float sc[4];
#pragma unroll
            for (int j = 0; j < 4; j++) {
                const int nj = l32 + 32 * j;
                const bool m = (nj == 0) ? (depot_r != 0.f)
                    : (((mb4 >> j) & 1u) || (d4[j] > cap));
                const float raw = fmaf(cap, scapr[j], s1r[j]);
                sc[j] = (nj < 100 && !m) ? raw : NEGV;
            }
#pragma unroll
            for (int j = 0; j < 4; j++) a[j] = __expf(sc[j]);
            tot = (a[0] + a[1]) + (a[2] + a[3]);
        }

        // ---- C: glimpse cols 4F..4F+3 (unnormalized attn via shfl); the
        //      width-32 tot butterfly overlaps the shfl+FMA chain
        float4 gp4 = make_float4(0.f, 0.f, 0.f, 0.f);
#pragma unroll
        for (int m = 0; m < 13; m++) {
            const int src = ((f >> 2) << 5) | (8 * (m & 3) + g);
            const float av = __shfl(a[m >> 2], src, 64);
            gp4.x = fmaf(av, Vreg[m].x, gp4.x);
            gp4.y = fmaf(av, Vreg[m].y, gp4.y);
            gp4.z = fmaf(av, Vreg[m].z, gp4.z);
            gp4.w = fmaf(av, Vreg[m].w, gp4.w);
        }
#pragma unroll
        for (int off = 1; off <= 16; off <<= 1)
            tot += __shfl_xor(tot, off, 32);    // per-head tot (indep chain)
#pragma unroll
        for (int off = 8; off <= 32; off <<= 1) {
            gp4.x += __shfl_xor(gp4.x, off, 64);
            gp4.y += __shfl_xor(gp4.y, off, 64);
            gp4.z += __shfl_xor(gp4.z, off, 64);
            gp4.w += __shfl_xor(gp4.w, off, 64);
        }
        // normalize by this col's head-tot (head of col F = 2w + (f>>2))
        {
            const float th = __shfl(tot, ((f >> 2) << 5) | l32, 64);
            const float rt = fast_rcp(th);
            gp4.x *= rt; gp4.y *= rt; gp4.z *= rt; gp4.w *= rt;
        }

        // ---- U: u-partials over this wave's 32 cols -> u_buf rows 2w,2w+1
        {
            float pm[13];
#pragma unroll
            for (int m = 0; m < 13; m++) {
                float p = gp4.x * K2r[m].x;
                p = fmaf(gp4.y, K2r[m].y, p);
                p = fmaf(gp4.z, K2r[m].z, p);
                p = fmaf(gp4.w, K2r[m].w, p);
                pm[m] = p;
            }
#pragma unroll
            for (int m = 0; m < 13; m++) pm[m] += __shfl_xor(pm[m], 1, 64);
#pragma unroll
            for (int m = 0; m < 13; m++) pm[m] += __shfl_xor(pm[m], 2, 64);
            if ((f & 3) == 0) {
                const int r = w * 2 + (f >> 2);
#pragma unroll
                for (int m = 0; m < 13; m++) {
                    const int n = g + 8 * m;
                    if (n < 100) u_buf[ub + r * 100 + n] = pm[m];
                }
            }
        }
        __syncthreads();

        // ---- E: fused argmax + lse in ONE butterfly (u bounded by tanh, so
        //      sum exp(v) needs no max-sub; logp = bv - log(sum))
        float v0, v1 = -3.0e38f;
        {
            float s8 = 0.f;
#pragma unroll
            for (int r = 0; r < 8; r++) s8 += u_buf[ub + r * 100 + l];
            const float u0 = tanh10(s8 * inv_sqrt_h);
            const bool m0 = (l == 0) ? (depot_r != 0.f) : (me0 || de0 > cap);
            v0 = (m0 ? NEGV : u0) * invT;
            if (l + 64 < 100) {
                float t8 = 0.f;
#pragma unroll
                for (int r = 0; r < 8; r++) t8 += u_buf[ub + r * 100 + l + 64];
                const float u1 = tanh10(t8 * inv_sqrt_h);
                const bool m1 = (me1 || de1 > cap);
                v1 = (m1 ? NEGV : u1) * invT;
            }
        }
        unsigned long long p;
        float tt;
        {
            const unsigned long long p0 =
                ((unsigned long long)fkey(v0) << 32) | (unsigned)(127 - l);
            const unsigned long long p1 =
                ((unsigned long long)fkey(v1) << 32) | (unsigned)(127 - (l + 64));
            p = (p1 > p0) ? p1 : p0;
            tt = __expf(v0) + ((l + 64 < 100) ? __expf(v1) : 0.f);
        }
#pragma unroll
        for (int off = 1; off < 64; off <<= 1) {
            const unsigned lo = __shfl_xor((unsigned)p, off, 64);
            const unsigned hi = __shfl_xor((unsigned)(p >> 32), off, 64);
            const float    to = __shfl_xor(tt, off, 64);
            const unsigned long long po = ((unsigned long long)hi << 32) | lo;
            tt += to;
            if (po > p) p = po;
        }
        const int idx = 127 - (int)(unsigned)(p & 0xffffffffULL);
        const float bv = funkey((unsigned)(p >> 32));

        // prefetch next S1 row ASAP (state-update ops hide part of the load)
#pragma unroll
        for (int j = 0; j < 4; j++) {
            const int nj = l32 + 32 * j;
            if (nj < 100)
                s1r[j] = S1b[(size_t)idx * 800 + h8 * 100 + nj];
        }

        const float d_sel = (idx >= 64) ? de1 : de0;
        const float dmd_idx = __shfl(d_sel, idx & 63, 64);
        const float capn = (idx == 0) ? base_cap : (cap - dmd_idx);

        if (visited_r < 99) logp_r += bv - __logf(tt);
        visited_r += (idx > 0) ? 1 : 0;
        me0 = me0 || (l == idx && idx > 0);
        me1 = me1 || (l + 64 == idx);
#pragma unroll
        for (int j = 0; j < 4; j++)
            if ((l32 + 32 * j) == idx && idx > 0) mb4 |= (1u << j);

        const bool am0 = (l == 0) ? true : (me0 || de0 > capn);
        const bool am1 = (l + 64 >= 100) ? true : (me1 || de1 > capn);
        const bool allc = __all(am0 && am1);
        depot_r = allc ? 0.f : ((idx == 0) ? 1.f : 0.f);
        cap_r = capn;
        if (tid == 0) act_sh[s] = idx;
        ub ^= 800;
    }

    __syncthreads();
    for (int t = tid; t < nsteps; t += 256)
        out[(size_t)b * nsteps + t] = (float)act_sh[t];
    if (tid == 0)
        out[(size_t)gridDim.x * nsteps + b] = logp_r;
}

// ---------------- launcher ---------------------------------------------------
extern "C" void kernel_launch(void* const* d_in, const int* in_sizes, int n_in,
                              void* d_out, int out_size, void* d_ws, size_t ws_size,
                              hipStream_t stream) {
    const float* enc    = (const float*)d_in[0];
    const float* pool   = (const float*)d_in[1];
    const float* cap    = (const float*)d_in[2];
    const float* demand = (const float*)d_in[3];
    const float* fc_w   = (const float*)d_in[4];
    const float* fc1_w  = (const float*)d_in[5];
    const float* Wq     = (const float*)d_in[6];
    const float* Wk     = (const float*)d_in[7];
    const float* Wv     = (const float*)d_in[8];
    const float* Wo     = (const float*)d_in[9];
    const float* Wk2    = (const float*)d_in[10];
    const int*   nst    = (const int*)d_in[11];
    const int*   Tp     = (const int*)d_in[12];
    float* out = (float*)d_out;

    prep_kernel<<<641, 128, 0, stream>>>(Wk, Wv, Wk2, Wo, Wq, fc_w, fc1_w);
    gemm_kernel<<<dim3(800, 4), 256, 0, stream>>>(enc, 0);
    gemm_kernel<<<dim3(8, 1),   256, 0, stream>>>(pool, 1);
    s1_kernel<<<1024, 256, 0, stream>>>();
    decode_kernel<<<1024, 256, 0, stream>>>(cap, demand, nst, Tp, out);
}

// Round 8
// 853.640 us; speedup vs baseline: 1.4641x; 1.1988x over previous
//
#include <hip/hip_runtime.h>
#include <math.h>

#define NNODE 100
#define NEGV  -1000000000.0f

// ---------------- static device workspace (ws_size unknown -> avoid d_ws) ---
__device__ float g_Wall [128 * 512];            // [k][c]: Wk^T | Wv^T | G | M^T
__device__ float g_Wall2[128 * 128];            // [k][c]: (Wq@fc1_w)^T
__device__ float g_qcap [128];                  // Wq @ fc_w[:,H]
__device__ float g_C    [(size_t)102400 * 512]; // per (b,n): K|V|K2W|Q1
__device__ float g_qpool[(size_t)1024 * 128];   // per b
__device__ float g_S1   [(size_t)1024 * 100 * 800]; // [b][m][h*100+n]
__device__ float g_Scap [(size_t)1024 * 800];       // [b][h*100+n]

__device__ __forceinline__ float fast_rcp(float x) { return __builtin_amdgcn_rcpf(x); }
__device__ __forceinline__ float tanh10(float z) {
    // 10*tanh(z) = 10 - 20/(exp(2z)+1); exp->inf => 10, exp->0 => -10 (safe)
    const float e2 = __expf(2.0f * z);
    return fmaf(-20.0f, __builtin_amdgcn_rcpf(e2 + 1.0f), 10.0f);
}
// monotone order-preserving float->uint key (totally ordered, no NaNs here)
__device__ __forceinline__ unsigned fkey(float v) {
    const unsigned u = __float_as_uint(v);
    return (u & 0x80000000u) ? ~u : (u | 0x80000000u);
}
__device__ __forceinline__ float funkey(unsigned k) {
    return __uint_as_float((k & 0x80000000u) ? (k ^ 0x80000000u) : ~k);
}

// ---- DPP cross-lane (VALU-speed, vs ~120cyc LDS-path ds_swizzle/permute) ----
// quad_perm xor1 = 0xB1, xor2 = 0x4E; row_ror:4 = 0x124, row_ror:8 = 0x128
// (row_ror:8 within a 16-lane row IS exact xor8; ror4+ror8 give full 16-lane
//  coverage for reductions, association varies per-lane by <=1 ulp)
template<int CTRL>
__device__ __forceinline__ int dpp_i(int v) {
    return __builtin_amdgcn_update_dpp(0, v, CTRL, 0xF, 0xF, true);
}
template<int CTRL>
__device__ __forceinline__ float dpp_f(float v) {
    return __uint_as_float((unsigned)dpp_i<CTRL>(__float_as_int(v)));
}
__device__ __forceinline__ float swz16_f(float v) {   // exact xor16 (within 32)
    return __uint_as_float(
        (unsigned)__builtin_amdgcn_ds_swizzle(__float_as_int(v), 0x401F));
}

// ---------------- kernel 1: fold weights -----------------------------------
__global__ __launch_bounds__(128) void prep_kernel(
    const float* __restrict__ Wk,  const float* __restrict__ Wv,
    const float* __restrict__ Wk2, const float* __restrict__ Wo,
    const float* __restrict__ Wq,  const float* __restrict__ fc_w,
    const float* __restrict__ fc1_w)
{
    const int c = blockIdx.x;
    const int k = threadIdx.x;
    if (c < 128) {
        g_Wall[k * 512 + c] = Wk[c * 128 + k];
    } else if (c < 256) {
        g_Wall[k * 512 + c] = Wv[(c - 128) * 128 + k];
    } else if (c < 384) {                           // G = Wk2^T @ Wo
        const int cc = c - 256;
        float acc = 0.f;
        for (int h = 0; h < 128; h++)
            acc = fmaf(Wk2[h * 128 + k], Wo[h * 128 + cc], acc);
        g_Wall[k * 512 + c] = acc;
    } else if (c < 512) {                           // M^T, M = Wq@fc_w[:,:128]
        const int cc = c - 384;
        float acc = 0.f;
        for (int j = 0; j < 128; j++)
            acc = fmaf(Wq[cc * 128 + j], fc_w[j * 129 + k], acc);
        g_Wall[k * 512 + c] = acc;
    } else if (c == 512) {                          // qcap = Wq @ fc_w[:,128]
        float acc = 0.f;
        for (int j = 0; j < 128; j++)
            acc = fmaf(Wq[k * 128 + j], fc_w[j * 129 + 128], acc);
        g_qcap[k] = acc;
    } else {                                        // (Wq@fc1_w)^T
        const int cc = c - 513;
        float acc = 0.f;
        for (int j = 0; j < 128; j++)
            acc = fmaf(Wq[cc * 128 + j], fc1_w[j * 128 + k], acc);
        g_Wall2[k * 128 + cc] = acc;
    }
}

// ---------------- kernel 2: fp32 tiled GEMM, k-chunked (33 KB LDS) ----------
__global__ __launch_bounds__(256) void gemm_kernel(const float* __restrict__ A,
                                                   int mode)
{
    const float* __restrict__ W = mode ? g_Wall2 : g_Wall;
    float* __restrict__ C       = mode ? g_qpool : g_C;
    const int ncols             = mode ? 128 : 512;
    const int m0 = blockIdx.x * 128, n0 = blockIdx.y * 128;

    __shared__ __align__(16) float At[32 * 132];   // [k_local][m]
    __shared__ __align__(16) float Ws[32 * 128];   // [k_local][n]
    const int tid = threadIdx.x;
    const int tm = tid >> 5, tn = tid & 31;
    const int mb = tm * 16, nb = tn * 4;
    float4 acc[16];
#pragma unroll
    for (int i = 0; i < 16; i++) acc[i] = make_float4(0.f, 0.f, 0.f, 0.f);

    for (int kc = 0; kc < 4; kc++) {
        for (int f = tid; f < 1024; f += 256) {
            const int r = f >> 3, q8 = f & 7;
            float4 a = *(const float4*)&A[(size_t)(m0 + r) * 128 + kc * 32 + q8 * 4];
            At[(q8 * 4 + 0) * 132 + r] = a.x;
            At[(q8 * 4 + 1) * 132 + r] = a.y;
            At[(q8 * 4 + 2) * 132 + r] = a.z;
            At[(q8 * 4 + 3) * 132 + r] = a.w;
            const int kl = f >> 5, q = f & 31;
            *(float4*)&Ws[kl * 128 + q * 4] =
                *(const float4*)&W[(size_t)(kc * 32 + kl) * ncols + n0 + q * 4];
        }
        __syncthreads();
        for (int k = 0; k < 32; k++) {
            const float4 w = *(float4*)&Ws[k * 128 + nb];
#pragma unroll
            for (int i = 0; i < 16; i += 4) {
                const float4 a = *(float4*)&At[k * 132 + mb + i];
                acc[i + 0].x = fmaf(a.x, w.x, acc[i + 0].x);
                acc[i + 0].y = fmaf(a.x, w.y, acc[i + 0].y);
                acc[i + 0].z = fmaf(a.x, w.z, acc[i + 0].z);
                acc[i + 0].w = fmaf(a.x, w.w, acc[i + 0].w);
                acc[i + 1].x = fmaf(a.y, w.x, acc[i + 1].x);
                acc[i + 1].y = fmaf(a.y, w.y, acc[i + 1].y);
                acc[i + 1].z = fmaf(a.y, w.z, acc[i + 1].z);
                acc[i + 1].w = fmaf(a.y, w.w, acc[i + 1].w);
                acc[i + 2].x = fmaf(a.z, w.x, acc[i + 2].x);
                acc[i + 2].y = fmaf(a.z, w.y, acc[i + 2].y);
                acc[i + 2].z = fmaf(a.z, w.z, acc[i + 2].z);
                acc[i + 2].w = fmaf(a.z, w.w, acc[i + 2].w);
                acc[i + 3].x = fmaf(a.w, w.x, acc[i + 3].x);
                acc[i + 3].y = fmaf(a.w, w.y, acc[i + 3].y);
                acc[i + 3].z = fmaf(a.w, w.z, acc[i + 3].z);
                acc[i + 3].w = fmaf(a.w, w.w, acc[i + 3].w);
            }
        }
        __syncthreads();
    }
#pragma unroll
    for (int i = 0; i < 16; i++)
        *(float4*)&C[(size_t)(m0 + mb + i) * ncols + n0 + nb] = acc[i];
}

// ---------------- kernel 2.5: per-batch score fold --------------------------
__global__ __launch_bounds__(256) void s1_kernel()
{
    const int b = blockIdx.x;
    const int tid = threadIdx.x;
    const int h = tid >> 5, l32 = tid & 31;
    const float* __restrict__ Crow = &g_C[(size_t)b * 100 * 512];

    __shared__ __align__(16) float Q1sh[NNODE * 128];
    for (int f = tid; f < 3200; f += 256) {
        const int n = f >> 5, c4 = f & 31;
        *(float4*)&Q1sh[n * 128 + c4 * 4] =
            *(const float4*)&Crow[(size_t)n * 512 + 384 + c4 * 4];
    }
    __syncthreads();

    float4 kr[4][4];
    int nn[4];
#pragma unroll
    for (int j = 0; j < 4; j++) {
        nn[j] = l32 + 32 * j;
#pragma unroll
        for (int i = 0; i < 4; i++) {
            kr[j][i] = (nn[j] < 100)
                ? *(const float4*)&Crow[(size_t)nn[j] * 512 + h * 16 + i * 4]
                : make_float4(0.f, 0.f, 0.f, 0.f);
        }
    }
    float4 qc[4], qp[4];
#pragma unroll
    for (int i = 0; i < 4; i++) {
        qc[i] = *(const float4*)&g_qcap[h * 16 + i * 4];
        qp[i] = *(const float4*)&g_qpool[(size_t)b * 128 + h * 16 + i * 4];
    }
    float sp[4];
#pragma unroll
    for (int j = 0; j < 4; j++) {
        float dc = 0.f, dp = 0.f;
#pragma unroll
        for (int i = 0; i < 4; i++) {
            dc = fmaf(kr[j][i].x, qc[i].x, dc); dc = fmaf(kr[j][i].y, qc[i].y, dc);
            dc = fmaf(kr[j][i].z, qc[i].z, dc); dc = fmaf(kr[j][i].w, qc[i].w, dc);
            dp = fmaf(kr[j][i].x, qp[i].x, dp); dp = fmaf(kr[j][i].y, qp[i].y, dp);
            dp = fmaf(kr[j][i].z, qp[i].z, dp); dp = fmaf(kr[j][i].w, qp[i].w, dp);
        }
        sp[j] = dp;
        if (nn[j] < 100)
            g_Scap[(size_t)b * 800 + h * 100 + nn[j]] = dc * 0.25f;
    }

    float* __restrict__ S1b = &g_S1[(size_t)b * 80000];
    for (int m = 0; m < 100; m++) {
        float4 q[4];
#pragma unroll
        for (int i = 0; i < 4; i++)
            q[i] = *(float4*)&Q1sh[m * 128 + h * 16 + i * 4];
#pragma unroll
        for (int j = 0; j < 4; j++) {
            if (nn[j] < 100) {
                float d = 0.f;
#pragma unroll
                for (int i = 0; i < 4; i++) {
                    d = fmaf(kr[j][i].x, q[i].x, d); d = fmaf(kr[j][i].y, q[i].y, d);
                    d = fmaf(kr[j][i].z, q[i].z, d); d = fmaf(kr[j][i].w, q[i].w, d);
                }
                S1b[(size_t)m * 800 + h * 100 + nn[j]] = (d + sp[j]) * 0.25f;
            }
        }
    }
}

// ---------------- kernel 3: sequential decode, 1 barrier/step ----------------
// R7 structure with DPP-accelerated reductions (quad_perm/row_ror replace
// LDS-path ds_swizzle for stages 1,2,4,8).
__global__ __launch_bounds__(256) void decode_kernel(
    const float* __restrict__ capacity, const float* __restrict__ demand,
    const int* __restrict__ nsteps_p, const int* __restrict__ T_p,
    float* __restrict__ out)
{
    __shared__ float u_buf[2 * 800];    // [parity][r<8][n<100]
    __shared__ float demand_sh[NNODE];
    __shared__ int   act_sh[512];

    const int tid = threadIdx.x;
    const int b   = blockIdx.x;
    const int nsteps = nsteps_p[0];
    const float invT = 1.0f / (float)T_p[0];
    const float base_cap = capacity[0];
    const float inv_sqrt_h = 0.08838834764831845f;  // 1/sqrt(128)

    const float4* __restrict__ C4  = (const float4*)&g_C[(size_t)b * 100 * 512];
    const float*  __restrict__ S1b = &g_S1[(size_t)b * 80000];

    const int w = tid >> 6, l = tid & 63;
    const int g = l >> 3, f = l & 7;
    const int F = 8 * w + f;                 // global float4 col 0..31
    const int h8 = tid >> 5, l32 = tid & 31; // B mapping: head h8, nodes l32+32j

    // ---- persistent registers
    float4 Vreg[13], K2r[13];
#pragma unroll
    for (int m = 0; m < 13; m++) {
        const int n = g + 8 * m;
        const bool v = n < 100;
        Vreg[m] = v ? C4[(size_t)n * 128 + 32 + F] : make_float4(0.f, 0.f, 0.f, 0.f);
        K2r[m]  = v ? C4[(size_t)n * 128 + 64 + F] : make_float4(0.f, 0.f, 0.f, 0.f);
    }
    float s1r[4], scapr[4], d4[4];
#pragma unroll
    for (int j = 0; j < 4; j++) {
        const int nj = l32 + 32 * j;
        const bool v = nj < 100;
        scapr[j] = v ? g_Scap[(size_t)b * 800 + h8 * 100 + nj] : 0.f;
        s1r[j]   = v ? S1b[h8 * 100 + nj] : 0.f;
        d4[j]    = v ? demand[b * 100 + nj] : 1.0e30f;
    }
    const float de0 = demand[b * 100 + l];
    const float de1 = (l + 64 < 100) ? demand[b * 100 + l + 64] : 1.0e30f;
    for (int n = tid; n < 100; n += 256) demand_sh[n] = demand[b * 100 + n];
    bool me0 = false, me1 = false;      // mask1 for nodes l, l+64
    unsigned mb4 = 0;                   // mask1 bits for B's 4 nodes
    float cap_r = capacity[b];
    float depot_r;
    {
        const bool am0 = (l == 0) ? true : (de0 > cap_r);
        const bool am1 = (l + 64 >= 100) ? true : (de1 > cap_r);
        depot_r = __all(am0 && am1) ? 0.f : 1.f;
    }
    float logp_r = 0.f;
    int visited_r = 0;
    int ub = 0;
    __syncthreads();

    for (int s = 0; s < nsteps; s++) {
        const float cap = cap_r;

        // ---- B: masked scores + raw exp (no max-sub; masked -> exp = 0)
        float a[4];
        float tot;
        {
            float sc[4];
#pragma unroll
            for (int j = 0; j < 4; j++) {
                const int nj = l32 + 32 * j;
                const bool m = (nj == 0) ? (depot_r != 0.f)
                    : (((mb4 >> j) & 1u) || (d4[j] > cap));
                const float raw = fmaf(cap, scapr[j], s1r[j]);
                sc[j] = (nj < 100 && !m) ? raw : NEGV;
            }
#pragma unroll
            for (int j = 0; j < 4; j++) a[j] = __expf(sc[j]);
            tot = (a[0] + a[1]) + (a[2] + a[3]);
        }

        // ---- C: glimpse cols 4F..4F+3 (unnormalized attn via shfl); the
        //      width-32 tot reduction (DPP+swizzle) overlaps the shfl chain
        float4 gp4 = make_float4(0.f, 0.f, 0.f, 0.f);
#pragma unroll
        for (int m = 0; m < 13; m++) {
            const int src = ((f >> 2) << 5) | (8 * (m & 3) + g);
            const float av = __shfl(a[m >> 2], src, 64);
            gp4.x = fmaf(av, Vreg[m].x, gp4.x);
            gp4.y = fmaf(av, Vreg[m].y, gp4.y);
            gp4.z = fmaf(av, Vreg[m].z, gp4.z);
            gp4.w = fmaf(av, Vreg[m].w, gp4.w);
        }
        // tot: quad xor1,xor2 (exact) + ror4,ror8 (full-16) + xor16 swizzle
        tot += dpp_f<0xB1>(tot);
        tot += dpp_f<0x4E>(tot);
        tot += dpp_f<0x124>(tot);
        tot += dpp_f<0x128>(tot);
        tot += swz16_f(tot);
        // gp butterfly: xor8 via row_ror:8 (exact), xor16 swizzle, xor32 shfl
        gp4.x += dpp_f<0x128>(gp4.x);
        gp4.y += dpp_f<0x128>(gp4.y);
        gp4.z += dpp_f<0x128>(gp4.z);
        gp4.w += dpp_f<0x128>(gp4.w);
        gp4.x += swz16_f(gp4.x);
        gp4.y += swz16_f(gp4.y);
        gp4.z += swz16_f(gp4.z);
        gp4.w += swz16_f(gp4.w);
        gp4.x += __shfl_xor(gp4.x, 32, 64);
        gp4.y += __shfl_xor(gp4.y, 32, 64);
        gp4.z += __shfl_xor(gp4.z, 32, 64);
        gp4.w += __shfl_xor(gp4.w, 32, 64);
        // normalize by this col's head-tot (head of col F = 2w + (f>>2))
        {
            const float th = __shfl(tot, ((f >> 2) << 5) | l32, 64);
            const float rt = fast_rcp(th);
            gp4.x *= rt; gp4.y *= rt; gp4.z *= rt; gp4.w *= rt;
        }

        // ---- U: u-partials over this wave's 32 cols -> u_buf rows 2w,2w+1
        {
            float pm[13];
#pragma unroll
            for (int m = 0; m < 13; m++) {
                float p = gp4.x * K2r[m].x;
                p = fmaf(gp4.y, K2r[m].y, p);
                p = fmaf(gp4.z, K2r[m].z, p);
                p = fmaf(gp4.w, K2r[m].w, p);
                pm[m] = p;
            }
#pragma unroll
            for (int m = 0; m < 13; m++) pm[m] += dpp_f<0xB1>(pm[m]);  // xor1
#pragma unroll
            for (int m = 0; m < 13; m++) pm[m] += dpp_f<0x4E>(pm[m]);  // xor2
            if ((f & 3) == 0) {
                const int r = w * 2 + (f >> 2);
#pragma unroll
                for (int m = 0; m < 13; m++) {
                    const int n = g + 8 * m;
                    if (n < 100) u_buf[ub + r * 100 + n] = pm[m];
                }
            }
        }
        __syncthreads();

        // ---- E: fused argmax + lse in ONE reduction (DPP-accelerated)
        float v0, v1 = -3.0e38f;
        {
            float s8 = 0.f;
#pragma unroll
            for (int r = 0; r < 8; r++) s8 += u_buf[ub + r * 100 + l];
            const float u0 = tanh10(s8 * inv_sqrt_h);
            const bool m0 = (l == 0) ? (depot_r != 0.f) : (me0 || de0 > cap);
            v0 = (m0 ? NEGV : u0) * invT;
            if (l + 64 < 100) {
                float t8 = 0.f;
#pragma unroll
                for (int r = 0; r < 8; r++) t8 += u_buf[ub + r * 100 + l + 64];
                const float u1 = tanh10(t8 * inv_sqrt_h);
                const bool m1 = (me1 || de1 > cap);
                v1 = (m1 ? NEGV : u1) * invT;
            }
        }
        unsigned long long p;
        float tt;
        {
            const unsigned long long p0 =
                ((unsigned long long)fkey(v0) << 32) | (unsigned)(127 - l);
            const unsigned long long p1 =
                ((unsigned long long)fkey(v1) << 32) | (unsigned)(127 - (l + 64));
            p = (p1 > p0) ? p1 : p0;
            tt = __expf(v0) + ((l + 64 < 100) ? __expf(v1) : 0.f);
        }
        // DPP stages: quad xor1, quad xor2, ror4, ror8 (full 16-lane coverage)
#define E_DPP_STAGE(CTRL)                                                     \
        {                                                                     \
            const int lo = dpp_i<CTRL>((int)(unsigned)p);                     \
            const int hi = dpp_i<CTRL>((int)(unsigned)(p >> 32));             \
            const float tn = dpp_f<CTRL>(tt);                                 \
            const unsigned long long po =                                     \
                ((unsigned long long)(unsigned)hi << 32) | (unsigned)lo;      \
            tt += tn;                                                         \
            if (po > p) p = po;                                               \
        }
        E_DPP_STAGE(0xB1)
        E_DPP_STAGE(0x4E)
        E_DPP_STAGE(0x124)
        E_DPP_STAGE(0x128)
#undef E_DPP_STAGE
        {   // xor16 via ds_swizzle (exact)
            const int lo = __builtin_amdgcn_ds_swizzle((int)(unsigned)p, 0x401F);
            const int hi = __builtin_amdgcn_ds_swizzle((int)(unsigned)(p >> 32), 0x401F);
            const float tn = swz16_f(tt);
            const unsigned long long po =
                ((unsigned long long)(unsigned)hi << 32) | (unsigned)lo;
            tt += tn;
            if (po > p) p = po;
        }
        {   // xor32 via shfl (ds_permute)
            const unsigned lo = __shfl_xor((unsigned)p, 32, 64);
            const unsigned hi = __shfl_xor((unsigned)(p >> 32), 32, 64);
            const float tn = __shfl_xor(tt, 32, 64);
            const unsigned long long po = ((unsigned long long)hi << 32) | lo;
            tt += tn;
            if (po > p) p = po;
        }
        const int idx = 127 - (int)(unsigned)(p & 0xffffffffULL);
        const float bv = funkey((unsigned)(p >> 32));

        // prefetch next S1 row ASAP (state-update ops hide part of the load)
#pragma unroll
        for (int j = 0; j < 4; j++) {
            const int nj = l32 + 32 * j;
            if (nj < 100)
                s1r[j] = S1b[(size_t)idx * 800 + h8 * 100 + nj];
        }

        const float dmd_idx = demand_sh[idx];       // uniform addr -> broadcast
        const float capn = (idx == 0) ? base_cap : (cap - dmd_idx);

        if (visited_r < 99) logp_r += bv - __logf(tt);
        visited_r += (idx > 0) ? 1 : 0;
        me0 = me0 || (l == idx && idx > 0);
        me1 = me1 || (l + 64 == idx);
#pragma unroll
        for (int j = 0; j < 4; j++)
            if ((l32 + 32 * j) == idx && idx > 0) mb4 |= (1u << j);

        const bool am0 = (l == 0) ? true : (me0 || de0 > capn);
        const bool am1 = (l + 64 >= 100) ? true : (me1 || de1 > capn);
        const bool allc = __all(am0 && am1);
        depot_r = allc ? 0.f : ((idx == 0) ? 1.f : 0.f);
        cap_r = capn;
        if (tid == 0) act_sh[s] = idx;
        ub ^= 800;
    }

    __syncthreads();
    for (int t = tid; t < nsteps; t += 256)
        out[(size_t)b * nsteps + t] = (float)act_sh[t];
    if (tid == 0)
        out[(size_t)gridDim.x * nsteps + b] = logp_r;
}

// ---------------- launcher ---------------------------------------------------
extern "C" void kernel_launch(void* const* d_in, const int* in_sizes, int n_in,
                              void* d_out, int out_size, void* d_ws, size_t ws_size,
                              hipStream_t stream) {
    const float* enc    = (const float*)d_in[0];
    const float* pool   = (const float*)d_in[1];
    const float* cap    = (const float*)d_in[2];
    const float* demand = (const float*)d_in[3];
    const float* fc_w   = (const float*)d_in[4];
    const float* fc1_w  = (const float*)d_in[5];
    const float* Wq     = (const float*)d_in[6];
    const float* Wk     = (const float*)d_in[7];
    const float* Wv     = (const float*)d_in[8];
    const float* Wo     = (const float*)d_in[9];
    const float* Wk2    = (const float*)d_in[10];
    const int*   nst    = (const int*)d_in[11];
    const int*   Tp     = (const int*)d_in[12];
    float* out = (float*)d_out;

    prep_kernel<<<641, 128, 0, stream>>>(Wk, Wv, Wk2, Wo, Wq, fc_w, fc1_w);
    gemm_kernel<<<dim3(800, 4), 256, 0, stream>>>(enc, 0);
    gemm_kernel<<<dim3(8, 1),   256, 0, stream>>>(pool, 1);
    s1_kernel<<<1024, 256, 0, stream>>>();
    decode_kernel<<<1024, 256, 0, stream>>>(cap, demand, nst, Tp, out);
}